// Round 1
// baseline (11018.292 us; speedup 1.0000x reference)
//
#include <hip/hip_runtime.h>
#include <hip/hip_bf16.h>
#include <math.h>

// Problem constants
#define BSZ 64
#define TT  512
#define DD  512
#define UU  512
#define NZ  2048   // 4*U

// ---------------------------------------------------------------------------
// Phase 1: zx = x @ Wk.  M=32768 (b*T+t), K=512, N=2048. fp32 tiled GEMM.
// BM=BN=64, BK=16, 256 threads, 4x4 microtile.
// ---------------------------------------------------------------------------
template <bool ZXBF16>
__global__ __launch_bounds__(256) void gemm_zx(const float* __restrict__ A,
                                               const float* __restrict__ B,
                                               void* __restrict__ Cout) {
  __shared__ float As[16][65];  // [k][m], padded
  __shared__ float Bs[16][64];  // [k][n]

  const int tid = threadIdx.x;
  const int tx = tid & 15;   // n group
  const int ty = tid >> 4;   // m group
  const int m0 = blockIdx.y * 64;
  const int n0 = blockIdx.x * 64;

  // loader indices
  const int lm  = tid >> 2;         // 0..63  A row in tile
  const int lk4 = (tid & 3) * 4;    // k chunk for A
  const int lk  = tid >> 4;         // 0..15  B row (k) in tile
  const int ln4 = (tid & 15) * 4;   // n chunk for B

  float acc[4][4] = {};

  for (int k0 = 0; k0 < DD; k0 += 16) {
    float4 av = *(const float4*)(A + (size_t)(m0 + lm) * DD + k0 + lk4);
    float4 bv = *(const float4*)(B + (size_t)(k0 + lk) * NZ + n0 + ln4);
    As[lk4 + 0][lm] = av.x;
    As[lk4 + 1][lm] = av.y;
    As[lk4 + 2][lm] = av.z;
    As[lk4 + 3][lm] = av.w;
    *(float4*)&Bs[lk][ln4] = bv;
    __syncthreads();
#pragma unroll
    for (int kk = 0; kk < 16; ++kk) {
      float a[4], b[4];
#pragma unroll
      for (int i = 0; i < 4; ++i) a[i] = As[kk][ty * 4 + i];
#pragma unroll
      for (int j = 0; j < 4; ++j) b[j] = Bs[kk][tx * 4 + j];
#pragma unroll
      for (int i = 0; i < 4; ++i)
#pragma unroll
        for (int j = 0; j < 4; ++j) acc[i][j] = fmaf(a[i], b[j], acc[i][j]);
    }
    __syncthreads();
  }

#pragma unroll
  for (int i = 0; i < 4; ++i) {
    const size_t row = (size_t)(m0 + ty * 4 + i) * NZ + n0 + tx * 4;
    if constexpr (ZXBF16) {
      __hip_bfloat16* C = (__hip_bfloat16*)Cout;
#pragma unroll
      for (int j = 0; j < 4; ++j) C[row + j] = __float2bfloat16(acc[i][j]);
    } else {
      float* C = (float*)Cout;
      *(float4*)&C[row] = make_float4(acc[i][0], acc[i][1], acc[i][2], acc[i][3]);
    }
  }
}

// ---------------------------------------------------------------------------
// Phase 2: one kernel per timestep.
// grid = (32 unit tiles of 16, 4 batch tiles of 16), 256 threads.
// thread (tb, tu) owns one (b,u): 4 gate dot-products of length 512.
// h tile staged in LDS (padded 513); Wr staged in 16-k chunks as [k][u][gate]
// so the 4 gate weights for a unit are one b128 read.
// ---------------------------------------------------------------------------
template <bool ZXBF16>
__global__ __launch_bounds__(256) void lstm_step(const void* __restrict__ zx_,
                                                 const float* __restrict__ Wr,
                                                 const float* __restrict__ bias,
                                                 const float* __restrict__ h_in,
                                                 float* __restrict__ h_out,
                                                 float* __restrict__ c,
                                                 int t) {
  const int u0 = blockIdx.x * 16;
  const int b0 = blockIdx.y * 16;
  const int tid = threadIdx.x;
  const int tu = tid & 15;   // unit within tile
  const int tb = tid >> 4;   // batch within tile

  __shared__ float hs[16][513];
  __shared__ float wrs[16][16][4];  // [k][u][gate]

  // stage h_in tile: 16 rows x 512 floats
  {
    const int b = tid >> 4;
    const int cg = tid & 15;  // 32 floats each
    const float4* src = (const float4*)(h_in + (size_t)(b0 + b) * UU);
#pragma unroll
    for (int j = 0; j < 8; ++j) {
      float4 v = src[cg * 8 + j];
      hs[b][cg * 32 + j * 4 + 0] = v.x;
      hs[b][cg * 32 + j * 4 + 1] = v.y;
      hs[b][cg * 32 + j * 4 + 2] = v.z;
      hs[b][cg * 32 + j * 4 + 3] = v.w;
    }
  }
  __syncthreads();

  float z0 = 0.f, z1 = 0.f, z2 = 0.f, z3 = 0.f;

  for (int k0 = 0; k0 < UU; k0 += 16) {
    // stage Wr[k0..k0+15][the 64 needed cols] -> wrs[k][u][g]
    {
      const int krow = tid >> 4;       // 0..15
      const int cg = tid & 15;
      const int g = cg >> 2;           // gate
      const int uu4 = (cg & 3) * 4;    // unit subgroup
      float4 v = *(const float4*)(Wr + (size_t)(k0 + krow) * NZ + g * UU + u0 + uu4);
      wrs[krow][uu4 + 0][g] = v.x;
      wrs[krow][uu4 + 1][g] = v.y;
      wrs[krow][uu4 + 2][g] = v.z;
      wrs[krow][uu4 + 3][g] = v.w;
    }
    __syncthreads();
#pragma unroll
    for (int kk = 0; kk < 16; ++kk) {
      const float hv = hs[tb][k0 + kk];
      z0 = fmaf(hv, wrs[kk][tu][0], z0);
      z1 = fmaf(hv, wrs[kk][tu][1], z1);
      z2 = fmaf(hv, wrs[kk][tu][2], z2);
      z3 = fmaf(hv, wrs[kk][tu][3], z3);
    }
    __syncthreads();
  }

  const int b = b0 + tb;
  const int u = u0 + tu;
  const size_t zbase = ((size_t)b * TT + t) * NZ;

  float zi, zf, zg, zo;
  if constexpr (ZXBF16) {
    const __hip_bfloat16* zx = (const __hip_bfloat16*)zx_;
    zi = z0 + __bfloat162float(zx[zbase + 0 * UU + u]) + bias[0 * UU + u];
    zf = z1 + __bfloat162float(zx[zbase + 1 * UU + u]) + bias[1 * UU + u];
    zg = z2 + __bfloat162float(zx[zbase + 2 * UU + u]) + bias[2 * UU + u];
    zo = z3 + __bfloat162float(zx[zbase + 3 * UU + u]) + bias[3 * UU + u];
  } else {
    const float* zx = (const float*)zx_;
    zi = z0 + zx[zbase + 0 * UU + u] + bias[0 * UU + u];
    zf = z1 + zx[zbase + 1 * UU + u] + bias[1 * UU + u];
    zg = z2 + zx[zbase + 2 * UU + u] + bias[2 * UU + u];
    zo = z3 + zx[zbase + 3 * UU + u] + bias[3 * UU + u];
  }

  const float ig = 1.f / (1.f + expf(-zi));
  const float fg = 1.f / (1.f + expf(-zf));
  const float gg = tanhf(zg);
  const float og = 1.f / (1.f + expf(-zo));

  const size_t ci = (size_t)b * UU + u;
  const float cn = fg * c[ci] + ig * gg;
  c[ci] = cn;
  h_out[ci] = og * tanhf(cn);
}

// ---------------------------------------------------------------------------
extern "C" void kernel_launch(void* const* d_in, const int* in_sizes, int n_in,
                              void* d_out, int out_size, void* d_ws, size_t ws_size,
                              hipStream_t stream) {
  const float* x    = (const float*)d_in[0];
  const float* Wk   = (const float*)d_in[1];
  const float* Wr   = (const float*)d_in[2];
  const float* bias = (const float*)d_in[3];
  float* out = (float*)d_out;

  const size_t zx_f32_bytes = (size_t)BSZ * TT * NZ * sizeof(float);  // 256 MiB
  const size_t hc_bytes = (size_t)BSZ * UU * sizeof(float);           // 128 KiB

  char* ws = (char*)d_ws;
  const bool use_bf16_zx = (ws_size < zx_f32_bytes + 3 * hc_bytes);
  const size_t zx_bytes = use_bf16_zx ? zx_f32_bytes / 2 : zx_f32_bytes;

  void* zx = (void*)ws;
  float* h0 = (float*)(ws + zx_bytes);
  float* h1 = h0 + (size_t)BSZ * UU;
  float* c  = h1 + (size_t)BSZ * UU;

  hipMemsetAsync(h0, 0, hc_bytes, stream);
  hipMemsetAsync(c, 0, hc_bytes, stream);

  dim3 ggrid(NZ / 64, (BSZ * TT) / 64);  // 32 x 512
  if (use_bf16_zx)
    gemm_zx<true><<<ggrid, 256, 0, stream>>>(x, Wk, zx);
  else
    gemm_zx<false><<<ggrid, 256, 0, stream>>>(x, Wk, zx);

  dim3 sgrid(UU / 16, BSZ / 16);  // 32 x 4 = 128 blocks
  for (int t = 0; t < TT; ++t) {
    const float* hin = (t & 1) ? h1 : h0;
    float* hout = (t == TT - 1) ? out : ((t & 1) ? h0 : h1);
    if (use_bf16_zx)
      lstm_step<true><<<sgrid, 256, 0, stream>>>(zx, Wr, bias, hin, hout, c, t);
    else
      lstm_step<false><<<sgrid, 256, 0, stream>>>(zx, Wr, bias, hin, hout, c, t);
  }
}

// Round 2
// 10758.311 us; speedup vs baseline: 1.0242x; 1.0242x over previous
//
#include <hip/hip_runtime.h>
#include <hip/hip_bf16.h>
#include <math.h>

// Problem constants
#define BSZ 64
#define TT  512
#define DD  512
#define UU  512
#define NZ  2048   // 4*U

// Recurrence partition
#define NBG    4     // batch groups (16 batches each = MFMA m)
#define BG     16
#define NSL    32    // u-slices
#define USL    16    // units per slice
#define KSTEPS 16    // 512 / 32 (MFMA k=32)

using short8  = __attribute__((ext_vector_type(8))) short;
using floatx4 = __attribute__((ext_vector_type(4))) float;

// ---------------------------------------------------------------------------
// Phase 1: zx = x @ Wk.  M=32768, K=512, N=2048. fp32 tiled GEMM (unchanged).
// ---------------------------------------------------------------------------
template <bool ZXBF16>
__global__ __launch_bounds__(256) void gemm_zx(const float* __restrict__ A,
                                               const float* __restrict__ B,
                                               void* __restrict__ Cout) {
  __shared__ float As[16][65];
  __shared__ float Bs[16][64];

  const int tid = threadIdx.x;
  const int tx = tid & 15;
  const int ty = tid >> 4;
  const int m0 = blockIdx.y * 64;
  const int n0 = blockIdx.x * 64;

  const int lm  = tid >> 2;
  const int lk4 = (tid & 3) * 4;
  const int lk  = tid >> 4;
  const int ln4 = (tid & 15) * 4;

  float acc[4][4] = {};

  for (int k0 = 0; k0 < DD; k0 += 16) {
    float4 av = *(const float4*)(A + (size_t)(m0 + lm) * DD + k0 + lk4);
    float4 bv = *(const float4*)(B + (size_t)(k0 + lk) * NZ + n0 + ln4);
    As[lk4 + 0][lm] = av.x;
    As[lk4 + 1][lm] = av.y;
    As[lk4 + 2][lm] = av.z;
    As[lk4 + 3][lm] = av.w;
    *(float4*)&Bs[lk][ln4] = bv;
    __syncthreads();
#pragma unroll
    for (int kk = 0; kk < 16; ++kk) {
      float a[4], b[4];
#pragma unroll
      for (int i = 0; i < 4; ++i) a[i] = As[kk][ty * 4 + i];
#pragma unroll
      for (int j = 0; j < 4; ++j) b[j] = Bs[kk][tx * 4 + j];
#pragma unroll
      for (int i = 0; i < 4; ++i)
#pragma unroll
        for (int j = 0; j < 4; ++j) acc[i][j] = fmaf(a[i], b[j], acc[i][j]);
    }
    __syncthreads();
  }

#pragma unroll
  for (int i = 0; i < 4; ++i) {
    const size_t row = (size_t)(m0 + ty * 4 + i) * NZ + n0 + tx * 4;
    if constexpr (ZXBF16) {
      __hip_bfloat16* C = (__hip_bfloat16*)Cout;
#pragma unroll
      for (int j = 0; j < 4; ++j) C[row + j] = __float2bfloat16(acc[i][j]);
    } else {
      float* C = (float*)Cout;
      *(float4*)&C[row] = make_float4(acc[i][0], acc[i][1], acc[i][2], acc[i][3]);
    }
  }
}

// ---------------------------------------------------------------------------
// Phase 2: ONE persistent kernel for the whole 512-step scan.
// Grid (NSL=32, NBG=4) = 128 blocks x 256 threads, 1 block/CU (135 KiB LDS).
// Block (sl, bg): batches [16*bg, 16*bg+16), units [16*sl, 16*sl+16).
// Wr slice resident in LDS as split-bf16 (hi/lo) in MFMA B-fragment order.
// h stored per-timestep in ws as split-bf16 planes; per-slice flags give
// release/acquire ordering across the 32 blocks of a batch-group.
// All 128 blocks are co-resident (128 <= 256 CUs, nothing else running), so
// the spin-flag protocol cannot deadlock; no ordering assumption beyond that.
// ---------------------------------------------------------------------------
__device__ __forceinline__ floatx4 mfma16(short8 a, short8 b, floatx4 c) {
  return __builtin_amdgcn_mfma_f32_16x16x32_bf16(a, b, c, 0, 0, 0);
}

template <bool ZXBF16>
__global__ __launch_bounds__(256) void lstm_persist(
    const void* __restrict__ zx_, const float* __restrict__ Wr,
    const float* __restrict__ bias, unsigned short* __restrict__ h_hi,
    unsigned short* __restrict__ h_lo, int* __restrict__ flags,
    float* __restrict__ out) {
  extern __shared__ char lds[];
  unsigned short* wr_hi = (unsigned short*)lds;              // [K][gate][lane][8]
  unsigned short* wr_lo = wr_hi + KSTEPS * 4 * 64 * 8;       // 32768 ushorts each
  float* z_ex = (float*)(wr_lo + KSTEPS * 4 * 64 * 8);       // [4][16][16]

  const int sl = blockIdx.x;   // u-slice 0..31
  const int bg = blockIdx.y;   // batch group 0..3
  const int tid = threadIdx.x;
  const int wave = tid >> 6;   // = gate index 0..3
  const int lane = tid & 63;
  const int u0 = sl * USL;

  // ---- one-time: preformat Wr slice into LDS (split bf16, B-frag order) ----
  {
    const int cidx = tid & 63;          // g*16+u within slice
    const int koff = tid >> 6;          // 0..3
    const int g = cidx >> 4, u = cidx & 15;
    const int col = g * UU + u0 + u;
    for (int k0 = 0; k0 < DD; k0 += 4) {
      const int k = k0 + koff;
      const float v = Wr[(size_t)k * NZ + col];
      const __hip_bfloat16 vh = __float2bfloat16(v);
      const float rem = v - __bfloat162float(vh);
      const __hip_bfloat16 vl = __float2bfloat16(rem);
      const int K = k >> 5, kg = (k >> 3) & 3, j = k & 7;
      const int off = ((K * 4 + g) * 64 + (kg * 16 + u)) * 8 + j;
      wr_hi[off] = *(const unsigned short*)&vh;
      wr_lo[off] = *(const unsigned short*)&vl;
    }
  }
  __syncthreads();

  // per-thread cell state: thread owns (b = tid>>4, u = tid&15)
  float c_state = 0.f;
  const int eb = tid >> 4, eu = tid & 15;

  const size_t plane_t = (size_t)NBG * BG * UU;  // 32768 elems per timestep
  int* myflag = flags + (bg * NSL + sl) * 16;
  int* grpflags = flags + bg * NSL * 16;

  // MFMA A-operand addressing: lane -> (m = lane&15, kgroup = lane>>4)
  const int am = lane & 15, akg = lane >> 4;

  // epilogue constant loads
  const float bias_i = bias[0 * UU + u0 + eu];
  const float bias_f = bias[1 * UU + u0 + eu];
  const float bias_g = bias[2 * UU + u0 + eu];
  const float bias_o = bias[3 * UU + u0 + eu];
  const size_t zrow = (size_t)(bg * BG + eb) * TT;

  for (int t = 0; t < TT; ++t) {
    // ---- wait for h_t from all 32 slice-blocks of this batch group ----
    if (t > 0) {
      if (tid < NSL) {
        const int* fp = grpflags + tid * 16;
        while (__hip_atomic_load(fp, __ATOMIC_ACQUIRE, __HIP_MEMORY_SCOPE_AGENT) < t)
          __builtin_amdgcn_s_sleep(2);
      }
      __syncthreads();
    }

    // ---- z[16b][16u] for this wave's gate via split-bf16 MFMA ----
    const unsigned short* Ahi =
        h_hi + (size_t)t * plane_t + (size_t)bg * BG * UU + am * UU + akg * 8;
    const unsigned short* Alo =
        h_lo + (size_t)t * plane_t + (size_t)bg * BG * UU + am * UU + akg * 8;

    floatx4 acc0 = {0.f, 0.f, 0.f, 0.f};
    floatx4 acc1 = {0.f, 0.f, 0.f, 0.f};
    floatx4 acc2 = {0.f, 0.f, 0.f, 0.f};
#pragma unroll
    for (int K = 0; K < KSTEPS; ++K) {
      const short8 ahi = *(const short8*)(Ahi + K * 32);
      const short8 alo = *(const short8*)(Alo + K * 32);
      const short8 bhi = *(const short8*)(wr_hi + ((K * 4 + wave) * 64 + lane) * 8);
      const short8 blo = *(const short8*)(wr_lo + ((K * 4 + wave) * 64 + lane) * 8);
      acc0 = mfma16(ahi, bhi, acc0);
      acc1 = mfma16(ahi, blo, acc1);
      acc2 = mfma16(alo, bhi, acc2);
    }
    // C layout: n = lane&15, m = (lane>>4)*4 + reg
#pragma unroll
    for (int r = 0; r < 4; ++r) {
      const int mm = (lane >> 4) * 4 + r;
      z_ex[(wave * 16 + mm) * 16 + (lane & 15)] = acc0[r] + acc1[r] + acc2[r];
    }
    __syncthreads();

    // ---- pointwise gates: thread = (eb, eu) ----
    float zi, zf, zg, zo;
    if constexpr (ZXBF16) {
      const unsigned short* zx = (const unsigned short*)zx_;
      const size_t zb = (zrow + t) * NZ + u0 + eu;
      zi = __bfloat162float(*(const __hip_bfloat16*)&zx[zb + 0 * UU]);
      zf = __bfloat162float(*(const __hip_bfloat16*)&zx[zb + 1 * UU]);
      zg = __bfloat162float(*(const __hip_bfloat16*)&zx[zb + 2 * UU]);
      zo = __bfloat162float(*(const __hip_bfloat16*)&zx[zb + 3 * UU]);
    } else {
      const float* zx = (const float*)zx_;
      const size_t zb = (zrow + t) * NZ + u0 + eu;
      zi = zx[zb + 0 * UU];
      zf = zx[zb + 1 * UU];
      zg = zx[zb + 2 * UU];
      zo = zx[zb + 3 * UU];
    }
    zi += z_ex[(0 * 16 + eb) * 16 + eu] + bias_i;
    zf += z_ex[(1 * 16 + eb) * 16 + eu] + bias_f;
    zg += z_ex[(2 * 16 + eb) * 16 + eu] + bias_g;
    zo += z_ex[(3 * 16 + eb) * 16 + eu] + bias_o;

    const float ig = 1.f / (1.f + expf(-zi));
    const float fg = 1.f / (1.f + expf(-zf));
    const float gg = tanhf(zg);
    const float og = 1.f / (1.f + expf(-zo));
    c_state = fg * c_state + ig * gg;
    const float hn = og * tanhf(c_state);

    // split h_new -> bf16 hi/lo planes for timestep t+1
    const __hip_bfloat16 hh = __float2bfloat16(hn);
    const float hrem = hn - __bfloat162float(hh);
    const __hip_bfloat16 hl = __float2bfloat16(hrem);
    const size_t widx =
        (size_t)(t + 1) * plane_t + (size_t)bg * BG * UU + (size_t)eb * UU + u0 + eu;
    h_hi[widx] = *(const unsigned short*)&hh;
    h_lo[widx] = *(const unsigned short*)&hl;

    if (t == TT - 1) out[(size_t)(bg * BG + eb) * UU + u0 + eu] = hn;

    // ---- release h_{t+1}: fence all threads' stores, then publish flag ----
    __threadfence();
    __syncthreads();
    if (tid == 0)
      __hip_atomic_store(myflag, t + 1, __ATOMIC_RELEASE, __HIP_MEMORY_SCOPE_AGENT);
    // z_ex WAR: next iteration writes z_ex only after the t>0 spin barrier.
  }
}

// ---------------------------------------------------------------------------
extern "C" void kernel_launch(void* const* d_in, const int* in_sizes, int n_in,
                              void* d_out, int out_size, void* d_ws, size_t ws_size,
                              hipStream_t stream) {
  const float* x    = (const float*)d_in[0];
  const float* Wk   = (const float*)d_in[1];
  const float* Wr   = (const float*)d_in[2];
  const float* bias = (const float*)d_in[3];
  float* out = (float*)d_out;

  const size_t plane_t = (size_t)NBG * BG * UU;                 // 32768
  const size_t hplane_bytes = (size_t)(TT + 1) * plane_t * 2;   // 32.06 MiB
  const size_t flags_bytes = (size_t)NBG * NSL * 16 * 4;        // 8 KiB
  const size_t zx_f32_bytes = (size_t)BSZ * TT * NZ * 4;        // 256 MiB

  const size_t need_f32 = zx_f32_bytes + 2 * hplane_bytes + flags_bytes;
  const bool use_bf16_zx = (ws_size < need_f32);
  const size_t zx_bytes = use_bf16_zx ? zx_f32_bytes / 2 : zx_f32_bytes;

  char* ws = (char*)d_ws;
  void* zx = (void*)ws;
  unsigned short* h_hi = (unsigned short*)(ws + zx_bytes);
  unsigned short* h_lo = (unsigned short*)(ws + zx_bytes + hplane_bytes);
  int* flags = (int*)(ws + zx_bytes + 2 * hplane_bytes);

  // zero h_0 planes (t=0 slab only) and flags
  hipMemsetAsync(h_hi, 0, plane_t * 2, stream);
  hipMemsetAsync(h_lo, 0, plane_t * 2, stream);
  hipMemsetAsync(flags, 0, flags_bytes, stream);

  dim3 ggrid(NZ / 64, (BSZ * TT) / 64);
  if (use_bf16_zx)
    gemm_zx<true><<<ggrid, 256, 0, stream>>>(x, Wk, zx);
  else
    gemm_zx<false><<<ggrid, 256, 0, stream>>>(x, Wk, zx);

  const int lds_bytes = KSTEPS * 4 * 64 * 8 * 2 * 2 + 4 * 16 * 16 * 4;  // 135168
  dim3 pgrid(NSL, NBG);
  if (use_bf16_zx) {
    hipFuncSetAttribute(reinterpret_cast<const void*>(lstm_persist<true>),
                        hipFuncAttributeMaxDynamicSharedMemorySize, lds_bytes);
    lstm_persist<true><<<pgrid, 256, lds_bytes, stream>>>(zx, Wr, bias, h_hi, h_lo,
                                                          flags, out);
  } else {
    hipFuncSetAttribute(reinterpret_cast<const void*>(lstm_persist<false>),
                        hipFuncAttributeMaxDynamicSharedMemorySize, lds_bytes);
    lstm_persist<false><<<pgrid, 256, lds_bytes, stream>>>(zx, Wr, bias, h_hi, h_lo,
                                                           flags, out);
  }
}

// Round 3
// 6999.462 us; speedup vs baseline: 1.5742x; 1.5370x over previous
//
#include <hip/hip_runtime.h>
#include <hip/hip_bf16.h>
#include <math.h>

// Problem constants
#define BSZ 64
#define TT  512
#define DD  512
#define UU  512
#define NZ  2048   // 4*U

#define NSL    32    // u-slices (= blocks)
#define USL    16    // units per slice
#define KSTEPS 16    // 512 / 32 (MFMA k=32)

using short8  = __attribute__((ext_vector_type(8))) short;
using floatx4 = __attribute__((ext_vector_type(4))) float;

// ---------------------------------------------------------------------------
// Phase 1: zx = x @ Wk.  M=32768, K=512, N=2048. fp32 tiled GEMM (unchanged).
// ---------------------------------------------------------------------------
template <bool ZXBF16>
__global__ __launch_bounds__(256) void gemm_zx(const float* __restrict__ A,
                                               const float* __restrict__ B,
                                               void* __restrict__ Cout) {
  __shared__ float As[16][65];
  __shared__ float Bs[16][64];

  const int tid = threadIdx.x;
  const int tx = tid & 15;
  const int ty = tid >> 4;
  const int m0 = blockIdx.y * 64;
  const int n0 = blockIdx.x * 64;

  const int lm  = tid >> 2;
  const int lk4 = (tid & 3) * 4;
  const int lk  = tid >> 4;
  const int ln4 = (tid & 15) * 4;

  float acc[4][4] = {};

  for (int k0 = 0; k0 < DD; k0 += 16) {
    float4 av = *(const float4*)(A + (size_t)(m0 + lm) * DD + k0 + lk4);
    float4 bv = *(const float4*)(B + (size_t)(k0 + lk) * NZ + n0 + ln4);
    As[lk4 + 0][lm] = av.x;
    As[lk4 + 1][lm] = av.y;
    As[lk4 + 2][lm] = av.z;
    As[lk4 + 3][lm] = av.w;
    *(float4*)&Bs[lk][ln4] = bv;
    __syncthreads();
#pragma unroll
    for (int kk = 0; kk < 16; ++kk) {
      float a[4], b[4];
#pragma unroll
      for (int i = 0; i < 4; ++i) a[i] = As[kk][ty * 4 + i];
#pragma unroll
      for (int j = 0; j < 4; ++j) b[j] = Bs[kk][tx * 4 + j];
#pragma unroll
      for (int i = 0; i < 4; ++i)
#pragma unroll
        for (int j = 0; j < 4; ++j) acc[i][j] = fmaf(a[i], b[j], acc[i][j]);
    }
    __syncthreads();
  }

#pragma unroll
  for (int i = 0; i < 4; ++i) {
    const size_t row = (size_t)(m0 + ty * 4 + i) * NZ + n0 + tx * 4;
    if constexpr (ZXBF16) {
      __hip_bfloat16* C = (__hip_bfloat16*)Cout;
#pragma unroll
      for (int j = 0; j < 4; ++j) C[row + j] = __float2bfloat16(acc[i][j]);
    } else {
      float* C = (float*)Cout;
      *(float4*)&C[row] = make_float4(acc[i][0], acc[i][1], acc[i][2], acc[i][3]);
    }
  }
}

// ---------------------------------------------------------------------------
// Phase 2: ONE persistent kernel, 32 blocks x 512 threads (1 CU each).
// Block sl owns units [16*sl, 16*sl+16) x 4 gates for ALL 64 batches.
// Wr slice resident in LDS (split-bf16 hi/lo, MFMA B-frag order, 128 KiB).
// h planes (hi/lo bf16, ushort[t][b=64][u=512]) live in ws; written as packed
// 32-bit agent-scope relaxed atomics (L2-bypass, fine-grained coherent), read
// as b128 after a single per-step acquire fence. Per-slice flags released
// after __syncthreads() (which drains vmcnt -> stores are at the coherence
// point before the flag store issues).
// 32 blocks <= 256 CUs: all co-resident, spin protocol cannot deadlock.
// ---------------------------------------------------------------------------
__device__ __forceinline__ floatx4 mfma16(short8 a, short8 b, floatx4 c) {
  return __builtin_amdgcn_mfma_f32_16x16x32_bf16(a, b, c, 0, 0, 0);
}

template <bool ZXBF16>
__global__ __launch_bounds__(512) void lstm_persist(
    const void* __restrict__ zx_, const float* __restrict__ Wr,
    const float* __restrict__ bias, unsigned short* __restrict__ h_hi,
    unsigned short* __restrict__ h_lo, int* __restrict__ flags,
    float* __restrict__ out) {
  extern __shared__ char lds[];
  unsigned short* wr_hi = (unsigned short*)lds;            // [K][g][lane][8]
  unsigned short* wr_lo = wr_hi + KSTEPS * 4 * 64 * 8;     // 32768 ushorts each
  float* z_ex = (float*)(wr_lo + KSTEPS * 4 * 64 * 8);     // [4 g][64 b][16 u]

  const int sl = blockIdx.x;
  const int tid = threadIdx.x;
  const int wave = tid >> 6;          // 0..7
  const int lane = tid & 63;
  const int u0 = sl * USL;

  // ---- one-time: preformat Wr slice into LDS (split bf16, B-frag order) ----
  {
    const int cidx = tid & 63;        // g*16+u within slice
    const int koff = tid >> 6;        // 0..7
    const int g = cidx >> 4, u = cidx & 15;
    const int col = g * UU + u0 + u;
    for (int k0 = 0; k0 < DD; k0 += 8) {
      const int k = k0 + koff;
      const float v = Wr[(size_t)k * NZ + col];
      const __hip_bfloat16 vh = __float2bfloat16(v);
      const float rem = v - __bfloat162float(vh);
      const __hip_bfloat16 vl = __float2bfloat16(rem);
      const int K = k >> 5, kg = (k >> 3) & 3, j = k & 7;
      const int off = ((K * 4 + g) * 64 + (kg * 16 + u)) * 8 + j;
      wr_hi[off] = *(const unsigned short*)&vh;
      wr_lo[off] = *(const unsigned short*)&vl;
    }
  }
  __syncthreads();

  // MFMA wave mapping: mt = wave>>1 (batch tile), gates {gp, gp+1}
  const int mt = wave >> 1;
  const int gp = (wave & 1) * 2;
  const int am = lane & 15, akg = lane >> 4;
  const size_t arow = (size_t)(mt * 16 + am) * UU + akg * 8;

  // epilogue mapping: thread -> (b, unit pair)
  const int eb = tid >> 3;            // 0..63
  const int up = tid & 7;             // unit pair 0..7 -> units 2up, 2up+1
  const float2 bias_i = *(const float2*)(bias + 0 * UU + u0 + 2 * up);
  const float2 bias_f = *(const float2*)(bias + 1 * UU + u0 + 2 * up);
  const float2 bias_g = *(const float2*)(bias + 2 * UU + u0 + 2 * up);
  const float2 bias_o = *(const float2*)(bias + 3 * UU + u0 + 2 * up);
  float c0 = 0.f, c1 = 0.f;
  const size_t plane_t = (size_t)BSZ * UU;          // 32768 ushorts / timestep
  const int wword = eb * (UU / 2) + (u0 >> 1) + up; // packed word idx in plane

  for (int t = 0; t < TT; ++t) {
    // ---- acquire h_t: relaxed poll, then ONE acquire fence ----
    if (tid < NSL) {
      const int* fp = flags + tid * 16;
      while (__hip_atomic_load(fp, __ATOMIC_RELAXED, __HIP_MEMORY_SCOPE_AGENT) < t) {
      }
    }
    __syncthreads();
    __builtin_amdgcn_fence(__ATOMIC_ACQUIRE, "agent");

    // ---- z for (mt, gp..gp+1) via split-bf16 MFMA ----
    const unsigned short* Ahi = h_hi + (size_t)t * plane_t + arow;
    const unsigned short* Alo = h_lo + (size_t)t * plane_t + arow;
    floatx4 a0g0 = {0, 0, 0, 0}, a1g0 = {0, 0, 0, 0}, a2g0 = {0, 0, 0, 0};
    floatx4 a0g1 = {0, 0, 0, 0}, a1g1 = {0, 0, 0, 0}, a2g1 = {0, 0, 0, 0};
#pragma unroll 4
    for (int K = 0; K < KSTEPS; ++K) {
      const short8 ahi = *(const short8*)(Ahi + K * 32);
      const short8 alo = *(const short8*)(Alo + K * 32);
      const short8 bhi0 = *(const short8*)(wr_hi + ((K * 4 + gp) * 64 + lane) * 8);
      const short8 blo0 = *(const short8*)(wr_lo + ((K * 4 + gp) * 64 + lane) * 8);
      const short8 bhi1 = *(const short8*)(wr_hi + ((K * 4 + gp + 1) * 64 + lane) * 8);
      const short8 blo1 = *(const short8*)(wr_lo + ((K * 4 + gp + 1) * 64 + lane) * 8);
      a0g0 = mfma16(ahi, bhi0, a0g0);
      a1g0 = mfma16(ahi, blo0, a1g0);
      a2g0 = mfma16(alo, bhi0, a2g0);
      a0g1 = mfma16(ahi, bhi1, a0g1);
      a1g1 = mfma16(ahi, blo1, a1g1);
      a2g1 = mfma16(alo, bhi1, a2g1);
    }
    // C layout: u = lane&15, b-in-tile = (lane>>4)*4 + r
#pragma unroll
    for (int r = 0; r < 4; ++r) {
      const int bb = mt * 16 + (lane >> 4) * 4 + r;
      z_ex[((gp + 0) * 64 + bb) * 16 + (lane & 15)] = a0g0[r] + a1g0[r] + a2g0[r];
      z_ex[((gp + 1) * 64 + bb) * 16 + (lane & 15)] = a0g1[r] + a1g1[r] + a2g1[r];
    }
    __syncthreads();

    // ---- pointwise gates: thread = (eb, units 2up, 2up+1) ----
    float2 zi, zf, zg, zo;
    {
      const size_t zb = ((size_t)eb * TT + t) * NZ + u0 + 2 * up;
      if constexpr (ZXBF16) {
        const unsigned short* zx = (const unsigned short*)zx_;
        ushort2 vi = *(const ushort2*)(zx + zb + 0 * UU);
        ushort2 vf = *(const ushort2*)(zx + zb + 1 * UU);
        ushort2 vg = *(const ushort2*)(zx + zb + 2 * UU);
        ushort2 vo = *(const ushort2*)(zx + zb + 3 * UU);
        zi = make_float2(__bfloat162float(*(__hip_bfloat16*)&vi.x),
                         __bfloat162float(*(__hip_bfloat16*)&vi.y));
        zf = make_float2(__bfloat162float(*(__hip_bfloat16*)&vf.x),
                         __bfloat162float(*(__hip_bfloat16*)&vf.y));
        zg = make_float2(__bfloat162float(*(__hip_bfloat16*)&vg.x),
                         __bfloat162float(*(__hip_bfloat16*)&vg.y));
        zo = make_float2(__bfloat162float(*(__hip_bfloat16*)&vo.x),
                         __bfloat162float(*(__hip_bfloat16*)&vo.y));
      } else {
        const float* zx = (const float*)zx_;
        zi = *(const float2*)(zx + zb + 0 * UU);
        zf = *(const float2*)(zx + zb + 1 * UU);
        zg = *(const float2*)(zx + zb + 2 * UU);
        zo = *(const float2*)(zx + zb + 3 * UU);
      }
    }
    const float2 ri = *(const float2*)&z_ex[(0 * 64 + eb) * 16 + 2 * up];
    const float2 rf = *(const float2*)&z_ex[(1 * 64 + eb) * 16 + 2 * up];
    const float2 rg = *(const float2*)&z_ex[(2 * 64 + eb) * 16 + 2 * up];
    const float2 ro = *(const float2*)&z_ex[(3 * 64 + eb) * 16 + 2 * up];

    const float i0 = 1.f / (1.f + expf(-(zi.x + ri.x + bias_i.x)));
    const float i1 = 1.f / (1.f + expf(-(zi.y + ri.y + bias_i.y)));
    const float f0 = 1.f / (1.f + expf(-(zf.x + rf.x + bias_f.x)));
    const float f1 = 1.f / (1.f + expf(-(zf.y + rf.y + bias_f.y)));
    const float g0 = tanhf(zg.x + rg.x + bias_g.x);
    const float g1 = tanhf(zg.y + rg.y + bias_g.y);
    const float o0 = 1.f / (1.f + expf(-(zo.x + ro.x + bias_o.x)));
    const float o1 = 1.f / (1.f + expf(-(zo.y + ro.y + bias_o.y)));
    c0 = f0 * c0 + i0 * g0;
    c1 = f1 * c1 + i1 * g1;
    const float h0 = o0 * tanhf(c0);
    const float h1 = o1 * tanhf(c1);

    // split-bf16 publish (packed pair words, agent-scope relaxed = L2-bypass)
    const __hip_bfloat16 h0h = __float2bfloat16(h0);
    const __hip_bfloat16 h1h = __float2bfloat16(h1);
    const __hip_bfloat16 h0l = __float2bfloat16(h0 - __bfloat162float(h0h));
    const __hip_bfloat16 h1l = __float2bfloat16(h1 - __bfloat162float(h1h));
    const unsigned int whi =
        (unsigned int)*(const unsigned short*)&h0h |
        ((unsigned int)*(const unsigned short*)&h1h << 16);
    const unsigned int wlo =
        (unsigned int)*(const unsigned short*)&h0l |
        ((unsigned int)*(const unsigned short*)&h1l << 16);
    unsigned int* phi = (unsigned int*)(h_hi + (size_t)(t + 1) * plane_t) + wword;
    unsigned int* plo = (unsigned int*)(h_lo + (size_t)(t + 1) * plane_t) + wword;
    __hip_atomic_store(phi, whi, __ATOMIC_RELAXED, __HIP_MEMORY_SCOPE_AGENT);
    __hip_atomic_store(plo, wlo, __ATOMIC_RELAXED, __HIP_MEMORY_SCOPE_AGENT);

    if (t == TT - 1) {
      out[(size_t)eb * UU + u0 + 2 * up + 0] = h0;
      out[(size_t)eb * UU + u0 + 2 * up + 1] = h1;
    }

    // ---- release: barrier drains vmcnt (stores at coherence point) ----
    __syncthreads();
    if (tid == 0)
      __hip_atomic_store(flags + sl * 16, t + 1, __ATOMIC_RELAXED,
                         __HIP_MEMORY_SCOPE_AGENT);
  }
}

// ---------------------------------------------------------------------------
extern "C" void kernel_launch(void* const* d_in, const int* in_sizes, int n_in,
                              void* d_out, int out_size, void* d_ws, size_t ws_size,
                              hipStream_t stream) {
  const float* x    = (const float*)d_in[0];
  const float* Wk   = (const float*)d_in[1];
  const float* Wr   = (const float*)d_in[2];
  const float* bias = (const float*)d_in[3];
  float* out = (float*)d_out;

  const size_t plane_t = (size_t)BSZ * UU;                      // 32768
  const size_t hplane_bytes = (size_t)(TT + 1) * plane_t * 2;   // 32.06 MiB
  const size_t flags_bytes = (size_t)NSL * 16 * 4;              // 2 KiB
  const size_t zx_f32_bytes = (size_t)BSZ * TT * NZ * 4;        // 256 MiB

  const size_t need_f32 = zx_f32_bytes + 2 * hplane_bytes + flags_bytes;
  const bool use_bf16_zx = (ws_size < need_f32);
  const size_t zx_bytes = use_bf16_zx ? zx_f32_bytes / 2 : zx_f32_bytes;

  char* ws = (char*)d_ws;
  void* zx = (void*)ws;
  unsigned short* h_hi = (unsigned short*)(ws + zx_bytes);
  unsigned short* h_lo = (unsigned short*)(ws + zx_bytes + hplane_bytes);
  int* flags = (int*)(ws + zx_bytes + 2 * hplane_bytes);

  hipMemsetAsync(h_hi, 0, plane_t * 2, stream);  // h_0 slab
  hipMemsetAsync(h_lo, 0, plane_t * 2, stream);
  hipMemsetAsync(flags, 0, flags_bytes, stream);

  dim3 ggrid(NZ / 64, (BSZ * TT) / 64);
  if (use_bf16_zx)
    gemm_zx<true><<<ggrid, 256, 0, stream>>>(x, Wk, zx);
  else
    gemm_zx<false><<<ggrid, 256, 0, stream>>>(x, Wk, zx);

  const int lds_bytes = KSTEPS * 4 * 64 * 8 * 2 * 2 + 4 * 64 * 16 * 4;  // 147456
  if (use_bf16_zx) {
    hipFuncSetAttribute(reinterpret_cast<const void*>(lstm_persist<true>),
                        hipFuncAttributeMaxDynamicSharedMemorySize, lds_bytes);
    lstm_persist<true><<<NSL, 512, lds_bytes, stream>>>(zx, Wr, bias, h_hi, h_lo,
                                                        flags, out);
  } else {
    hipFuncSetAttribute(reinterpret_cast<const void*>(lstm_persist<false>),
                        hipFuncAttributeMaxDynamicSharedMemorySize, lds_bytes);
    lstm_persist<false><<<NSL, 512, lds_bytes, stream>>>(zx, Wr, bias, h_hi, h_lo,
                                                         flags, out);
  }
}